// Round 3
// baseline (560.270 us; speedup 1.0000x reference)
//
#include <hip/hip_runtime.h>

// HierarchicalRouter: 32768 tokens x D=2048 fp32.
// Outputs (concat in d_out): final_weights [32768,2], dispatch_mask [32768,64], router_loss [1].
// R1 lesson: register spill => 1.9 GB scratch traffic. R2 lesson: LDS-staged weights cost
// 2 barriers/chunk; all waves stall on the stage's HBM round-trip (barrier-drain) => 150 us,
// 1.8 TB/s. R3: weights (160 KB total, 20 KB/chunk) are L1/L2-resident — load them directly
// from global per lane, NO barriers in the main loop; waves stream independently with ~24
// outstanding loads/chunk. launch_bounds(256,3): 168-VGPR cap, 12 waves/CU.

#define NTOK    32768
#define DIM     2048
#define NG      16      // router groups (rows of Wg)
#define GS      4       // experts per group (rows of We)
#define NE      64      // total experts
#define NR      20      // NG + GS stacked weight rows
#define DC      256     // D covered per wave per chunk (64 lanes x float4)
#define NCHUNK  (DIM / DC)
#define TPB     256
#define TPW     4       // tokens per wave
#define TPBK    16      // tokens per block (4 waves * 4)
#define NSHADOW 32      // shadow copies of expert_load to spread atomic contention

__global__ __launch_bounds__(TPB, 3) void router_main(
    const float* __restrict__ x,
    const float* __restrict__ Wg,
    const float* __restrict__ We,
    float* __restrict__ fw_out,
    float* __restrict__ dm_out,
    float* __restrict__ ws)
{
    __shared__ float lds_load[NE];    // per-block expert load
    __shared__ float lds_z;           // per-block z-loss partial

    const int tid  = threadIdx.x;
    const int lane = tid & 63;
    const int wave = tid >> 6;
    const long t_base = (long)blockIdx.x * TPBK + wave * TPW;

    if (tid < NE) lds_load[tid] = 0.0f;
    if (tid == 0) lds_z = 0.0f;

    float acc[TPW][NR];
    #pragma unroll
    for (int t = 0; t < TPW; ++t)
        #pragma unroll
        for (int r = 0; r < NR; ++r) acc[t][r] = 0.0f;

    const int d0 = lane * 4;   // this lane's float4 offset within a chunk

    for (int c = 0; c < NCHUNK; ++c) {
        const int dd = c * DC + d0;

        // x loads: 64 lanes x 16B = 1 KB contiguous per token (HBM stream)
        float4 xa[TPW];
        #pragma unroll
        for (int t = 0; t < TPW; ++t)
            xa[t] = *(const float4*)(x + (size_t)(t_base + t) * DIM + dd);

        // weight loads: direct from global; 20 KB chunk is L1-resident, no barriers
        #pragma unroll
        for (int r = 0; r < NR; ++r) {
            const float* src = (r < NG) ? (Wg + (size_t)r * DIM)
                                        : (We + (size_t)(r - NG) * DIM);
            float4 w = *(const float4*)(src + dd);
            #pragma unroll
            for (int t = 0; t < TPW; ++t) {
                acc[t][r] += xa[t].x * w.x + xa[t].y * w.y
                           + xa[t].z * w.z + xa[t].w * w.w;
            }
        }
    }

    // ---- full-wave butterfly reduce: all lanes converge to identical sums ----
    #pragma unroll
    for (int t = 0; t < TPW; ++t)
        #pragma unroll
        for (int r = 0; r < NR; ++r) {
            float v = acc[t][r];
            #pragma unroll
            for (int s = 32; s > 0; s >>= 1) v += __shfl_xor(v, s, 64);
            acc[t][r] = v;
        }

    // ---- epilogue: tokens sequentially; scalar-only state (lane-uniform values) ----
    #pragma unroll
    for (int t = 0; t < TPW; ++t) {
        // group softmax + top-1 (strict > = first-index-wins, matches np)
        float m16 = acc[t][0];
        #pragma unroll
        for (int r = 1; r < NG; ++r) m16 = fmaxf(m16, acc[t][r]);
        float den = 0.0f, bm = -1.0f; int gi = 0;
        #pragma unroll
        for (int r = 0; r < NG; ++r) {
            float e = expf(acc[t][r] - m16);
            den += e;
            if (e > bm) { bm = e; gi = r; }
        }
        float gw = bm / den;   // chosen_group_w (max softmax prob)

        // local softmax (4) + top-2
        float m4 = fmaxf(fmaxf(acc[t][NG + 0], acc[t][NG + 1]),
                         fmaxf(acc[t][NG + 2], acc[t][NG + 3]));
        float pr[GS]; float s4 = 0.0f;
        #pragma unroll
        for (int r = 0; r < GS; ++r) { pr[r] = expf(acc[t][NG + r] - m4); s4 += pr[r]; }
        float inv4 = 1.0f / s4;
        #pragma unroll
        for (int r = 0; r < GS; ++r) pr[r] *= inv4;

        int i0 = 0; float v0 = pr[0];
        #pragma unroll
        for (int r = 1; r < GS; ++r) if (pr[r] > v0) { v0 = pr[r]; i0 = r; }
        int i1 = -1; float v1 = -1.0f;
        #pragma unroll
        for (int r = 0; r < GS; ++r) if (r != i0 && pr[r] > v1) { v1 = pr[r]; i1 = r; }

        float nrm = v0 + v1 + 1e-7f;
        float sf0 = gw * (v0 / nrm);
        float sf1 = gw * (v1 / nrm);
        int   se0 = (gi << 2) + i0;
        int   se1 = (gi << 2) + i1;

        float sg = 0.0f;
        #pragma unroll
        for (int r = 0; r < NG; ++r) sg += acc[t][r] * acc[t][r];
        float sl = 0.0f;
        #pragma unroll
        for (int r = 0; r < GS; ++r) sl += acc[t][NG + r] * acc[t][NG + r];
        float sz = sg * (1.0f / 16.0f) + sl * 0.25f;   // per-token z contribution

        const long tok = t_base + t;
        if (lane < 16) {
            int col4 = lane * 4;
            float4 v;
            v.x = (col4 + 0 == se0) ? sf0 : (col4 + 0 == se1) ? sf1 : 0.0f;
            v.y = (col4 + 1 == se0) ? sf0 : (col4 + 1 == se1) ? sf1 : 0.0f;
            v.z = (col4 + 2 == se0) ? sf0 : (col4 + 2 == se1) ? sf1 : 0.0f;
            v.w = (col4 + 3 == se0) ? sf0 : (col4 + 3 == se1) ? sf1 : 0.0f;
            *(float4*)(dm_out + (size_t)tok * NE + col4) = v;  // 16 lanes x 16B = 256B row
        } else if (lane == 16) {
            *(float2*)(fw_out + tok * 2) = make_float2(sf0, sf1);
        } else if (lane == 17) {
            atomicAdd(&lds_load[se0], sf0);
        } else if (lane == 18) {
            atomicAdd(&lds_load[se1], sf1);
        } else if (lane == 19) {
            atomicAdd(&lds_z, sz);
        }
    }

    __syncthreads();
    if (tid < NE) atomicAdd(&ws[(blockIdx.x & (NSHADOW - 1)) * NE + tid], lds_load[tid]);
    if (tid == 0) atomicAdd(&ws[NSHADOW * NE], lds_z);
}

__global__ void router_finalize(const float* __restrict__ ws, float* __restrict__ out_loss)
{
    int e = threadIdx.x;  // 64 threads = 1 wave
    float load = 0.0f;
    #pragma unroll
    for (int s = 0; s < NSHADOW; ++s) load += ws[s * NE + e];
    float tot = load;
    #pragma unroll
    for (int s = 32; s > 0; s >>= 1) tot += __shfl_xor(tot, s, 64);
    float target = tot * (1.0f / NE);
    float dev = load - target;
    float sq = dev * dev;
    #pragma unroll
    for (int s = 32; s > 0; s >>= 1) sq += __shfl_xor(sq, s, 64);
    if (e == 0) {
        float lb = sq * (1.0f / NE);
        float z  = ws[NSHADOW * NE] * (1.0f / NTOK);
        out_loss[0] = 0.001f * (lb + z);
    }
}

extern "C" void kernel_launch(void* const* d_in, const int* in_sizes, int n_in,
                              void* d_out, int out_size, void* d_ws, size_t ws_size,
                              hipStream_t stream)
{
    const float* x  = (const float*)d_in[0];
    const float* Wg = (const float*)d_in[1];
    const float* We = (const float*)d_in[2];
    float* out = (float*)d_out;
    float* fw  = out;                                         // [32768, 2]
    float* dm  = out + (size_t)NTOK * 2;                      // [32768, 64]
    float* ls  = out + (size_t)NTOK * 2 + (size_t)NTOK * NE;  // [1]
    float* ws  = (float*)d_ws;

    hipMemsetAsync(ws, 0, (NSHADOW * NE + 1) * sizeof(float), stream);
    router_main<<<NTOK / TPBK, TPB, 0, stream>>>(x, Wg, We, fw, dm, ws);
    router_finalize<<<1, 64, 0, stream>>>(ws, ls);
}

// Round 4
// 517.384 us; speedup vs baseline: 1.0829x; 1.0829x over previous
//
#include <hip/hip_runtime.h>

// HierarchicalRouter: 32768 tokens x D=2048 fp32.
// Outputs (concat in d_out): final_weights [32768,2], dispatch_mask [32768,64], router_loss [1].
// R1 lesson: acc[4][20]+epilogue arrays spill => 1.9 GB scratch. R2: LDS-staged weights =
// 2 barriers/chunk barrier-drain => ~150 us. R3: barrier-free direct weight loads BUT TPW=4
// spilled again (VGPR=84 alloc, 239 MB scratch writes) => 298 us. The compiler settles at
// ~84 VGPRs regardless of launch_bounds, so per-lane state MUST fit under that.
// R4: TPW=2 -> acc=40 regs, total live ~60. Barrier-free main loop kept: weights (160 KB)
// are L1/L2-resident, each wave streams independently.

#define NTOK    32768
#define DIM     2048
#define NG      16      // router groups (rows of Wg)
#define GS      4       // experts per group (rows of We)
#define NE      64      // total experts
#define NR      20      // NG + GS stacked weight rows
#define DC      256     // D covered per wave per chunk (64 lanes x float4)
#define NCHUNK  (DIM / DC)
#define TPB     256
#define TPW     2       // tokens per wave (acc = TPW*20 = 40 VGPRs)
#define TPBK    8       // tokens per block (4 waves * 2)
#define NSHADOW 32      // shadow copies of expert_load to spread atomic contention

__global__ __launch_bounds__(TPB, 3) void router_main(
    const float* __restrict__ x,
    const float* __restrict__ Wg,
    const float* __restrict__ We,
    float* __restrict__ fw_out,
    float* __restrict__ dm_out,
    float* __restrict__ ws)
{
    __shared__ float lds_load[NE];    // per-block expert load
    __shared__ float lds_z;           // per-block z-loss partial

    const int tid  = threadIdx.x;
    const int lane = tid & 63;
    const int wave = tid >> 6;
    const long t_base = (long)blockIdx.x * TPBK + wave * TPW;

    if (tid < NE) lds_load[tid] = 0.0f;
    if (tid == 0) lds_z = 0.0f;

    float acc[TPW][NR];
    #pragma unroll
    for (int t = 0; t < TPW; ++t)
        #pragma unroll
        for (int r = 0; r < NR; ++r) acc[t][r] = 0.0f;

    const int d0 = lane * 4;                     // this lane's float4 offset within a chunk
    const float* xb0 = x + (size_t)t_base * DIM + d0;   // token 0 base (lane-adjusted)
    const float* xb1 = xb0 + DIM;                       // token 1 base

    for (int c = 0; c < NCHUNK; ++c) {
        const int dd = c * DC;

        // x loads: 64 lanes x 16B = 1 KB contiguous per token (HBM stream)
        float4 xa0 = *(const float4*)(xb0 + dd);
        float4 xa1 = *(const float4*)(xb1 + dd);

        // weight loads: direct from global; 20 KB chunk is L1-resident, no barriers
        #pragma unroll
        for (int r = 0; r < NR; ++r) {
            const float* src = (r < NG) ? (Wg + (size_t)r * DIM)
                                        : (We + (size_t)(r - NG) * DIM);
            float4 w = *(const float4*)(src + dd + d0);
            acc[0][r] += xa0.x * w.x + xa0.y * w.y + xa0.z * w.z + xa0.w * w.w;
            acc[1][r] += xa1.x * w.x + xa1.y * w.y + xa1.z * w.z + xa1.w * w.w;
        }
    }

    // ---- full-wave butterfly reduce: all lanes converge to identical sums ----
    #pragma unroll
    for (int t = 0; t < TPW; ++t)
        #pragma unroll
        for (int r = 0; r < NR; ++r) {
            float v = acc[t][r];
            #pragma unroll
            for (int s = 32; s > 0; s >>= 1) v += __shfl_xor(v, s, 64);
            acc[t][r] = v;
        }

    // ---- epilogue: tokens sequentially; scalar-only state (lane-uniform values) ----
    #pragma unroll
    for (int t = 0; t < TPW; ++t) {
        // group softmax + top-1 (strict > = first-index-wins, matches np)
        float m16 = acc[t][0];
        #pragma unroll
        for (int r = 1; r < NG; ++r) m16 = fmaxf(m16, acc[t][r]);
        float den = 0.0f, bm = -1.0f; int gi = 0;
        #pragma unroll
        for (int r = 0; r < NG; ++r) {
            float e = expf(acc[t][r] - m16);
            den += e;
            if (e > bm) { bm = e; gi = r; }
        }
        float gw = bm / den;   // chosen_group_w (max softmax prob)

        // local softmax (4) + top-2
        float m4 = fmaxf(fmaxf(acc[t][NG + 0], acc[t][NG + 1]),
                         fmaxf(acc[t][NG + 2], acc[t][NG + 3]));
        float pr[GS]; float s4 = 0.0f;
        #pragma unroll
        for (int r = 0; r < GS; ++r) { pr[r] = expf(acc[t][NG + r] - m4); s4 += pr[r]; }
        float inv4 = 1.0f / s4;
        #pragma unroll
        for (int r = 0; r < GS; ++r) pr[r] *= inv4;

        int i0 = 0; float v0 = pr[0];
        #pragma unroll
        for (int r = 1; r < GS; ++r) if (pr[r] > v0) { v0 = pr[r]; i0 = r; }
        int i1 = -1; float v1 = -1.0f;
        #pragma unroll
        for (int r = 0; r < GS; ++r) if (r != i0 && pr[r] > v1) { v1 = pr[r]; i1 = r; }

        float nrm = v0 + v1 + 1e-7f;
        float sf0 = gw * (v0 / nrm);
        float sf1 = gw * (v1 / nrm);
        int   se0 = (gi << 2) + i0;
        int   se1 = (gi << 2) + i1;

        float sg = 0.0f;
        #pragma unroll
        for (int r = 0; r < NG; ++r) sg += acc[t][r] * acc[t][r];
        float sl = 0.0f;
        #pragma unroll
        for (int r = 0; r < GS; ++r) sl += acc[t][NG + r] * acc[t][NG + r];
        float sz = sg * (1.0f / 16.0f) + sl * 0.25f;   // per-token z contribution

        const long tok = t_base + t;
        if (lane < 16) {
            int col4 = lane * 4;
            float4 v;
            v.x = (col4 + 0 == se0) ? sf0 : (col4 + 0 == se1) ? sf1 : 0.0f;
            v.y = (col4 + 1 == se0) ? sf0 : (col4 + 1 == se1) ? sf1 : 0.0f;
            v.z = (col4 + 2 == se0) ? sf0 : (col4 + 2 == se1) ? sf1 : 0.0f;
            v.w = (col4 + 3 == se0) ? sf0 : (col4 + 3 == se1) ? sf1 : 0.0f;
            *(float4*)(dm_out + (size_t)tok * NE + col4) = v;  // 16 lanes x 16B = 256B row
        } else if (lane == 16) {
            *(float2*)(fw_out + tok * 2) = make_float2(sf0, sf1);
        } else if (lane == 17) {
            atomicAdd(&lds_load[se0], sf0);
        } else if (lane == 18) {
            atomicAdd(&lds_load[se1], sf1);
        } else if (lane == 19) {
            atomicAdd(&lds_z, sz);
        }
    }

    __syncthreads();
    if (tid < NE) atomicAdd(&ws[(blockIdx.x & (NSHADOW - 1)) * NE + tid], lds_load[tid]);
    if (tid == 0) atomicAdd(&ws[NSHADOW * NE], lds_z);
}

__global__ void router_finalize(const float* __restrict__ ws, float* __restrict__ out_loss)
{
    int e = threadIdx.x;  // 64 threads = 1 wave
    float load = 0.0f;
    #pragma unroll
    for (int s = 0; s < NSHADOW; ++s) load += ws[s * NE + e];
    float tot = load;
    #pragma unroll
    for (int s = 32; s > 0; s >>= 1) tot += __shfl_xor(tot, s, 64);
    float target = tot * (1.0f / NE);
    float dev = load - target;
    float sq = dev * dev;
    #pragma unroll
    for (int s = 32; s > 0; s >>= 1) sq += __shfl_xor(sq, s, 64);
    if (e == 0) {
        float lb = sq * (1.0f / NE);
        float z  = ws[NSHADOW * NE] * (1.0f / NTOK);
        out_loss[0] = 0.001f * (lb + z);
    }
}

extern "C" void kernel_launch(void* const* d_in, const int* in_sizes, int n_in,
                              void* d_out, int out_size, void* d_ws, size_t ws_size,
                              hipStream_t stream)
{
    const float* x  = (const float*)d_in[0];
    const float* Wg = (const float*)d_in[1];
    const float* We = (const float*)d_in[2];
    float* out = (float*)d_out;
    float* fw  = out;                                         // [32768, 2]
    float* dm  = out + (size_t)NTOK * 2;                      // [32768, 64]
    float* ls  = out + (size_t)NTOK * 2 + (size_t)NTOK * NE;  // [1]
    float* ws  = (float*)d_ws;

    hipMemsetAsync(ws, 0, (NSHADOW * NE + 1) * sizeof(float), stream);
    router_main<<<NTOK / TPBK, TPB, 0, stream>>>(x, Wg, We, fw, dm, ws);
    router_finalize<<<1, 64, 0, stream>>>(ws, ls);
}